// Round 1
// baseline (1028.870 us; speedup 1.0000x reference)
//
#include <hip/hip_runtime.h>
#include <math.h>

#define N_NODES 50000
#define N_EDGES 800000
#define CLAMP_V 5.0f
#define EPS_V   1e-8f

// ============================================================================
// K1: QKV projection.  x(50000,64) @ [Wq|Wk|Wv](64,192) + bias -> qkv(50000,192)
// qkv row layout: [Q(64) | K(64) | V(64)], col = h*8+d (matches reshape(n,8,8)).
// block 192 threads (1 col each, 16 nodes), grid 3125.
// ============================================================================
__global__ __launch_bounds__(192) void qkv_kernel(
    const float* __restrict__ x,
    const float* __restrict__ Wq, const float* __restrict__ bq,
    const float* __restrict__ Wk, const float* __restrict__ bk,
    const float* __restrict__ Wv, const float* __restrict__ bv,
    float* __restrict__ qkv)
{
  __shared__ float sW[64][192];
  __shared__ float sb[192];
  __shared__ float sa[16][68];   // pad 68: 16B-aligned float4 rows
  const int t = threadIdx.x;
  for (int k = 0; k < 64; k++) {
    float w;
    if (t < 64)       w = Wq[k*64 + t];
    else if (t < 128) w = Wk[k*64 + (t-64)];
    else              w = Wv[k*64 + (t-128)];
    sW[k][t] = w;
  }
  sb[t] = (t < 64) ? bq[t] : (t < 128) ? bk[t-64] : bv[t-128];
  const int n0 = blockIdx.x * 16;                 // 3125*16 == 50000 exactly
  for (int idx = t; idx < 256; idx += 192) {      // 16 nodes x 16 k-quads
    int node = idx >> 4, kq = idx & 15;
    *(float4*)&sa[node][kq*4] = *(const float4*)&x[(size_t)(n0+node)*64 + kq*4];
  }
  __syncthreads();
  float acc[16];
  #pragma unroll
  for (int j = 0; j < 16; j++) acc[j] = 0.f;
  for (int k4 = 0; k4 < 16; k4++) {
    float wq[4];
    #pragma unroll
    for (int q = 0; q < 4; q++) wq[q] = sW[k4*4+q][t];
    #pragma unroll
    for (int jh = 0; jh < 2; jh++) {
      float4 av[8];
      #pragma unroll
      for (int jj = 0; jj < 8; jj++) av[jj] = *(const float4*)&sa[jh*8+jj][k4*4];
      #pragma unroll
      for (int jj = 0; jj < 8; jj++) {
        acc[jh*8+jj] += av[jj].x*wq[0] + av[jj].y*wq[1] + av[jj].z*wq[2] + av[jj].w*wq[3];
      }
    }
  }
  const float b = sb[t];
  #pragma unroll
  for (int j = 0; j < 16; j++) qkv[(size_t)(n0+j)*192 + t] = acc[j] + b;
}

// ============================================================================
// K2: edge kernel.  E_proj = edge_attr @ We + be, fused with
// score = signed_sqrt((K[src]+Q[dst])*E_w) + E_b  -> wE write,
// s = clip(sum_d score*Aw, +-5) -> sExp = exp(s).
// fp32 on purpose: signed-sqrt has derivative ~1/(2*sqrt(eps)) near 0, so
// bf16 GEMM error (~3e-3) would blow up to ~0.05 in wE.
// block 256, tile 128 edges x 128 cols, 8x8 per-thread micro-tile, grid 6250.
// thread map: te=t>>4 (8 edges each), g=t&15 -> h=g>>1, dq=g&1:
//   cols = E_w[h][dq*4..+3] (c=h*16+dq*4) and E_b (c+8)  -> both float4.
// ============================================================================
__global__ __launch_bounds__(256) void edge_kernel(
    const float* __restrict__ edge_attr,
    const int*   __restrict__ eidx,
    const float* __restrict__ We, const float* __restrict__ be,
    const float* __restrict__ Aw,
    const float* __restrict__ qkv,
    float* __restrict__ wE, float* __restrict__ sExp)
{
  __shared__ float sW[64][136];   // col c stored at c + 8*(c>>6): 2-way banks (free)
  __shared__ float sbe[128];
  __shared__ float sAw[64];       // Aw flat (d,h): [d*8+h]
  __shared__ float sA[128][68];   // a[e][k]; k-quad swizzled by (e>>3)&3 -> conflict-free b128
  const int t = threadIdx.x;
  for (int i = t; i < 2048; i += 256) {           // We: 64x128 floats as float4
    int k = i >> 5, c = (i & 31) * 4;
    *(float4*)&sW[k][c + 8*(c>>6)] = *(const float4*)&We[(size_t)k*128 + c];
  }
  if (t < 128)       sbe[t] = be[t];
  else if (t < 192)  sAw[t-128] = Aw[t-128];
  const int e0 = blockIdx.x * 128;                // 6250*128 == 800000 exactly
  for (int i = t; i < 2048; i += 256) {           // a-tile: 128 edges x 16 k-quads
    int e = i >> 4, kq = i & 15;
    *(float4*)&sA[e][(kq ^ ((e>>3)&3)) * 4] =
        *(const float4*)&edge_attr[(size_t)(e0+e)*64 + kq*4];
  }
  __syncthreads();
  const int te = t >> 4;
  const int g = t & 15, h = g >> 1, dq = g & 1;
  const int cw = h*16 + dq*4, cb = cw + 8;
  const int cwp = cw + 8*(h>>2), cbp = cb + 8*(h>>2);   // swizzled LDS cols
  const int swa = te & 3;
  float4 accw[8], accb[8];
  #pragma unroll
  for (int j = 0; j < 8; j++) { accw[j] = make_float4(0,0,0,0); accb[j] = make_float4(0,0,0,0); }
  for (int kq = 0; kq < 16; kq++) {
    float4 av[8];
    const int kcol = (kq ^ swa) * 4;
    #pragma unroll
    for (int j = 0; j < 8; j++) av[j] = *(const float4*)&sA[te*8+j][kcol];
    #pragma unroll
    for (int q = 0; q < 4; q++) {
      const int k = kq*4 + q;
      const float4 ww = *(const float4*)&sW[k][cwp];
      const float4 wb = *(const float4*)&sW[k][cbp];
      #pragma unroll
      for (int j = 0; j < 8; j++) {
        const float a = (q==0) ? av[j].x : (q==1) ? av[j].y : (q==2) ? av[j].z : av[j].w;
        accw[j].x += a*ww.x; accw[j].y += a*ww.y; accw[j].z += a*ww.z; accw[j].w += a*ww.w;
        accb[j].x += a*wb.x; accb[j].y += a*wb.y; accb[j].z += a*wb.z; accb[j].w += a*wb.w;
      }
    }
  }
  const float4 bw = *(const float4*)&sbe[cw];
  const float4 bb = *(const float4*)&sbe[cb];
  const int d0 = dq * 4;
  const float awc0 = sAw[(d0+0)*8+h], awc1 = sAw[(d0+1)*8+h];
  const float awc2 = sAw[(d0+2)*8+h], awc3 = sAw[(d0+3)*8+h];
  #pragma unroll
  for (int j = 0; j < 8; j++) {
    const int e   = e0 + te*8 + j;
    const int src = eidx[e];
    const int dst = eidx[N_EDGES + e];
    const float4 kv = *(const float4*)&qkv[(size_t)src*192 + 64 + h*8 + d0];
    const float4 qv = *(const float4*)&qkv[(size_t)dst*192 +      h*8 + d0];
    const float s0 = (kv.x+qv.x)*(accw[j].x+bw.x);
    const float s1 = (kv.y+qv.y)*(accw[j].y+bw.y);
    const float s2 = (kv.z+qv.z)*(accw[j].z+bw.z);
    const float s3 = (kv.w+qv.w)*(accw[j].w+bw.w);
    const float r0 = sqrtf(fmaxf(s0,0.f)+EPS_V) - sqrtf(fmaxf(-s0,0.f)+EPS_V) + (accb[j].x+bb.x);
    const float r1 = sqrtf(fmaxf(s1,0.f)+EPS_V) - sqrtf(fmaxf(-s1,0.f)+EPS_V) + (accb[j].y+bb.y);
    const float r2 = sqrtf(fmaxf(s2,0.f)+EPS_V) - sqrtf(fmaxf(-s2,0.f)+EPS_V) + (accb[j].z+bb.z);
    const float r3 = sqrtf(fmaxf(s3,0.f)+EPS_V) - sqrtf(fmaxf(-s3,0.f)+EPS_V) + (accb[j].w+bb.w);
    *(float4*)&wE[(size_t)e*64 + h*8 + d0] = make_float4(r0,r1,r2,r3);
    float ps = r0*awc0 + r1*awc1 + r2*awc2 + r3*awc3;
    ps += __shfl_xor(ps, 1, 64);                 // partner thread holds the other d-quad
    if (dq == 0) {
      const float sc = fminf(fmaxf(ps, -CLAMP_V), CLAMP_V);
      // segment-max subtraction dropped: s in [-5,5] so exp() is safe and the
      // result is mathematically identical (1e-16 denominator perturbation ~2e-12).
      sExp[(size_t)e*8 + h] = expf(sc);
    }
  }
}

// ============================================================================
// K3: CSR-by-dst build (count -> scan -> scatter). Avoids 102M float atomics.
// ============================================================================
__global__ __launch_bounds__(256) void count_kernel(const int* __restrict__ eidx,
                                                    int* __restrict__ deg)
{
  const int e = blockIdx.x*256 + threadIdx.x;
  if (e < N_EDGES) atomicAdd(&deg[eidx[N_EDGES + e]], 1);
}

__global__ __launch_bounds__(1024) void scan_kernel(const int* __restrict__ deg,
                                                    int* __restrict__ row_start,
                                                    int* __restrict__ cursor)
{
  __shared__ int buf[1024];
  __shared__ int carry;
  const int t = threadIdx.x;
  if (t == 0) carry = 0;
  __syncthreads();
  for (int base = 0; base < N_NODES; base += 1024) {
    const int i = base + t;
    const int v = (i < N_NODES) ? deg[i] : 0;
    buf[t] = v;
    __syncthreads();
    int sum = v;
    for (int off = 1; off < 1024; off <<= 1) {
      const int other = (t >= off) ? buf[t-off] : 0;
      __syncthreads();
      sum += other;
      buf[t] = sum;
      __syncthreads();
    }
    const int base_c = carry;
    const int excl = base_c + sum - v;
    if (i < N_NODES) { row_start[i] = excl; cursor[i] = excl; }
    __syncthreads();
    if (t == 1023) carry = base_c + sum;
    __syncthreads();
  }
  if (t == 0) row_start[N_NODES] = carry;
}

__global__ __launch_bounds__(256) void scatter_kernel(const int* __restrict__ eidx,
                                                      int* __restrict__ cursor,
                                                      int* __restrict__ edge_ord)
{
  const int e = blockIdx.x*256 + threadIdx.x;
  if (e < N_EDGES) {
    const int pos = atomicAdd(&cursor[eidx[N_EDGES + e]], 1);
    edge_ord[pos] = e;
  }
}

// ============================================================================
// K4: node aggregation. One wave per node, lane = h*8+d.
// denom = sum exp(s); attn = exp(s)/(denom+1e-16);
// wV = sum attn*V[src] + (sum attn*e_t) @ VeRow.  No atomics.
// ============================================================================
__global__ __launch_bounds__(256) void node_kernel(
    const int*   __restrict__ eidx,
    const int*   __restrict__ row_start,
    const int*   __restrict__ edge_ord,
    const float* __restrict__ sExp,
    const float* __restrict__ qkv,
    const float* __restrict__ wE,
    const float* __restrict__ VeRow,
    float* __restrict__ wV)
{
  __shared__ float sVe[512];                      // VeRow (8,8,8) flat [d][h][c]
  const int t = threadIdx.x;
  for (int i = t; i < 512; i += 256) sVe[i] = VeRow[i];
  __syncthreads();
  const int lane = t & 63;
  const int node = blockIdx.x*4 + (t >> 6);       // 12500*4 == 50000 exactly
  const int h = lane >> 3;
  const int rs = row_start[node], re = row_start[node+1];
  float denom = 0.f;
  for (int j = rs; j < re; j++)
    denom += sExp[(size_t)edge_ord[j]*8 + h];
  const float rden = 1.0f / (denom + 1e-16f);
  float accW = 0.f, accR = 0.f;
  for (int j = rs; j < re; j++) {
    const int eid = edge_ord[j];
    const float attn = sExp[(size_t)eid*8 + h] * rden;
    const int src = eidx[eid];
    accW += qkv[(size_t)src*192 + 128 + lane] * attn;   // V[src]
    accR += wE[(size_t)eid*64 + lane] * attn;           // e_t
  }
  float val = accW;
  #pragma unroll
  for (int dd = 0; dd < 8; dd++) {
    const float rv = __shfl(accR, h*8 + dd, 64);        // rowV[h][dd]
    val += rv * sVe[dd*64 + lane];                      // VeRow[dd][h][c]
  }
  wV[(size_t)node*64 + lane] = val;
}

// ============================================================================
// Launch. Workspace layout (bytes, needs ~67.9 MB):
//   qkv      @ 0           : 50000*192*4 = 38,400,000
//   sExp     @ 38,400,000  : 800000*8*4  = 25,600,000
//   deg      @ 64,000,000  : 50000*4     =    200,000
//   row_start@ 64,200,000  : 50001*4     =    200,004
//   cursor   @ 64,400,016  : 50000*4     =    200,000
//   edge_ord @ 64,600,016  : 800000*4    =  3,200,000
// d_out: wV (50000*64) then wE (800000*64), fp32.
// ============================================================================
extern "C" void kernel_launch(void* const* d_in, const int* in_sizes, int n_in,
                              void* d_out, int out_size, void* d_ws, size_t ws_size,
                              hipStream_t stream)
{
  const float* x         = (const float*)d_in[0];
  const float* edge_attr = (const float*)d_in[1];
  const int*   eidx      = (const int*)  d_in[2];
  const float* Wq        = (const float*)d_in[3];
  const float* bq        = (const float*)d_in[4];
  const float* Wk        = (const float*)d_in[5];
  const float* bk        = (const float*)d_in[6];
  const float* We        = (const float*)d_in[7];
  const float* be        = (const float*)d_in[8];
  const float* Wv        = (const float*)d_in[9];
  const float* bv        = (const float*)d_in[10];
  const float* Aw        = (const float*)d_in[11];
  const float* VeRow     = (const float*)d_in[12];

  float* out = (float*)d_out;
  float* wV  = out;
  float* wE  = out + (size_t)N_NODES * 64;

  char* ws = (char*)d_ws;
  float* qkv      = (float*)(ws);
  float* sExp     = (float*)(ws + 38400000);
  int*   deg      = (int*)  (ws + 64000000);
  int*   row_start= (int*)  (ws + 64200000);
  int*   cursor   = (int*)  (ws + 64400016);
  int*   edge_ord = (int*)  (ws + 64600016);

  hipMemsetAsync(deg, 0, N_NODES * sizeof(int), stream);
  qkv_kernel   <<<3125,  192, 0, stream>>>(x, Wq, bq, Wk, bk, Wv, bv, qkv);
  edge_kernel  <<<6250,  256, 0, stream>>>(edge_attr, eidx, We, be, Aw, qkv, wE, sExp);
  count_kernel <<<3125,  256, 0, stream>>>(eidx, deg);
  scan_kernel  <<<1,    1024, 0, stream>>>(deg, row_start, cursor);
  scatter_kernel<<<3125, 256, 0, stream>>>(eidx, cursor, edge_ord);
  node_kernel  <<<12500, 256, 0, stream>>>(eidx, row_start, edge_ord, sExp, qkv, wE, VeRow, wV);
}

// Round 2
// 866.846 us; speedup vs baseline: 1.1869x; 1.1869x over previous
//
#include <hip/hip_runtime.h>
#include <math.h>

#define N_NODES 50000
#define N_EDGES 800000
#define CLAMP_V 5.0f
#define EPS_V   1e-8f

// ============================================================================
// K1: QKV projection.  x(50000,64) @ [Wq|Wk|Wv](64,192) + bias -> qkv(50000,192)
// qkv row layout: [Q(64) | K(64) | V(64)], col = h*8+d (matches reshape(n,8,8)).
// ============================================================================
__global__ __launch_bounds__(192) void qkv_kernel(
    const float* __restrict__ x,
    const float* __restrict__ Wq, const float* __restrict__ bq,
    const float* __restrict__ Wk, const float* __restrict__ bk,
    const float* __restrict__ Wv, const float* __restrict__ bv,
    float* __restrict__ qkv)
{
  __shared__ float sW[64][192];
  __shared__ float sb[192];
  __shared__ float sa[16][68];
  const int t = threadIdx.x;
  for (int k = 0; k < 64; k++) {
    float w;
    if (t < 64)       w = Wq[k*64 + t];
    else if (t < 128) w = Wk[k*64 + (t-64)];
    else              w = Wv[k*64 + (t-128)];
    sW[k][t] = w;
  }
  sb[t] = (t < 64) ? bq[t] : (t < 128) ? bk[t-64] : bv[t-128];
  const int n0 = blockIdx.x * 16;
  for (int idx = t; idx < 256; idx += 192) {
    int node = idx >> 4, kq = idx & 15;
    *(float4*)&sa[node][kq*4] = *(const float4*)&x[(size_t)(n0+node)*64 + kq*4];
  }
  __syncthreads();
  float acc[16];
  #pragma unroll
  for (int j = 0; j < 16; j++) acc[j] = 0.f;
  for (int k4 = 0; k4 < 16; k4++) {
    float wq[4];
    #pragma unroll
    for (int q = 0; q < 4; q++) wq[q] = sW[k4*4+q][t];
    #pragma unroll
    for (int jh = 0; jh < 2; jh++) {
      float4 av[8];
      #pragma unroll
      for (int jj = 0; jj < 8; jj++) av[jj] = *(const float4*)&sa[jh*8+jj][k4*4];
      #pragma unroll
      for (int jj = 0; jj < 8; jj++) {
        acc[jh*8+jj] += av[jj].x*wq[0] + av[jj].y*wq[1] + av[jj].z*wq[2] + av[jj].w*wq[3];
      }
    }
  }
  const float b = sb[t];
  #pragma unroll
  for (int j = 0; j < 16; j++) qkv[(size_t)(n0+j)*192 + t] = acc[j] + b;
}

// ============================================================================
// K2: edge kernel, k-split staging (two 32-k phases, single LDS buffer).
// LDS: sW 32x136 (17.4K) + sA 128x32 XOR-swizzled (16K) + be/Aw = ~34.6KB
//   -> 4 blocks/CU (was 70.6KB -> 2 blocks/CU).
// fp32 on purpose: signed-sqrt derivative ~1/(2*sqrt(eps)) near 0 amplifies
// any GEMM error; bf16 would fail tolerance.
// ============================================================================
__global__ __launch_bounds__(256) void edge_kernel(
    const float* __restrict__ edge_attr,
    const int*   __restrict__ eidx,
    const float* __restrict__ We, const float* __restrict__ be,
    const float* __restrict__ Aw,
    const float* __restrict__ qkv,
    float* __restrict__ wE, float* __restrict__ sExp)
{
  __shared__ float sW[32][136];   // col c at c + 8*(c>>6): 16 read-cols hit 16 distinct bank-groups
  __shared__ float sA[128][32];   // k-quad XOR-swizzled by (row>>3)&3: conflict-free b128
  __shared__ float sbe[128];
  __shared__ float sAw[64];
  const int t = threadIdx.x;
  const int e0 = blockIdx.x * 128;
  const int te = t >> 4;
  const int g = t & 15, h = g >> 1, dq = g & 1;
  const int cw = h*16 + dq*4, cb = cw + 8;
  const int cwp = cw + 8*(h>>2), cbp = cb + 8*(h>>2);
  const int swa = te & 3;
  float4 accw[8], accb[8];
  #pragma unroll
  for (int j = 0; j < 8; j++) { accw[j] = make_float4(0,0,0,0); accb[j] = make_float4(0,0,0,0); }
  if (t < 128)       sbe[t] = be[t];
  else if (t < 192)  sAw[t-128] = Aw[t-128];

  for (int ph = 0; ph < 2; ph++) {
    if (ph) __syncthreads();                       // drain compute before overwrite
    for (int i = t; i < 1024; i += 256) {          // We rows [ph*32, ph*32+32)
      int k = i >> 5, c = (i & 31) * 4;
      *(float4*)&sW[k][c + 8*(c>>6)] = *(const float4*)&We[(size_t)(ph*32+k)*128 + c];
    }
    for (int i = t; i < 1024; i += 256) {          // A cols [ph*32, ph*32+32)
      int e = i >> 3, kq = i & 7;
      *(float4*)&sA[e][(kq ^ ((e>>3)&3)) * 4] =
          *(const float4*)&edge_attr[(size_t)(e0+e)*64 + ph*32 + kq*4];
    }
    __syncthreads();
    for (int kq = 0; kq < 8; kq++) {
      float4 av[8];
      const int kcol = (kq ^ swa) * 4;
      #pragma unroll
      for (int j = 0; j < 8; j++) av[j] = *(const float4*)&sA[te*8+j][kcol];
      #pragma unroll
      for (int q = 0; q < 4; q++) {
        const int k = kq*4 + q;
        const float4 ww = *(const float4*)&sW[k][cwp];
        const float4 wb = *(const float4*)&sW[k][cbp];
        #pragma unroll
        for (int j = 0; j < 8; j++) {
          const float a = (q==0) ? av[j].x : (q==1) ? av[j].y : (q==2) ? av[j].z : av[j].w;
          accw[j].x += a*ww.x; accw[j].y += a*ww.y; accw[j].z += a*ww.z; accw[j].w += a*ww.w;
          accb[j].x += a*wb.x; accb[j].y += a*wb.y; accb[j].z += a*wb.z; accb[j].w += a*wb.w;
        }
      }
    }
  }

  const float4 bw = *(const float4*)&sbe[cw];
  const float4 bb = *(const float4*)&sbe[cb];
  const int d0 = dq * 4;
  const float awc0 = sAw[(d0+0)*8+h], awc1 = sAw[(d0+1)*8+h];
  const float awc2 = sAw[(d0+2)*8+h], awc3 = sAw[(d0+3)*8+h];
  #pragma unroll
  for (int j = 0; j < 8; j++) {
    const int e   = e0 + te*8 + j;
    const int src = eidx[e];
    const int dst = eidx[N_EDGES + e];
    const float4 kv = *(const float4*)&qkv[(size_t)src*192 + 64 + h*8 + d0];
    const float4 qv = *(const float4*)&qkv[(size_t)dst*192 +      h*8 + d0];
    const float s0 = (kv.x+qv.x)*(accw[j].x+bw.x);
    const float s1 = (kv.y+qv.y)*(accw[j].y+bw.y);
    const float s2 = (kv.z+qv.z)*(accw[j].z+bw.z);
    const float s3 = (kv.w+qv.w)*(accw[j].w+bw.w);
    const float r0 = sqrtf(fmaxf(s0,0.f)+EPS_V) - sqrtf(fmaxf(-s0,0.f)+EPS_V) + (accb[j].x+bb.x);
    const float r1 = sqrtf(fmaxf(s1,0.f)+EPS_V) - sqrtf(fmaxf(-s1,0.f)+EPS_V) + (accb[j].y+bb.y);
    const float r2 = sqrtf(fmaxf(s2,0.f)+EPS_V) - sqrtf(fmaxf(-s2,0.f)+EPS_V) + (accb[j].z+bb.z);
    const float r3 = sqrtf(fmaxf(s3,0.f)+EPS_V) - sqrtf(fmaxf(-s3,0.f)+EPS_V) + (accb[j].w+bb.w);
    *(float4*)&wE[(size_t)e*64 + h*8 + d0] = make_float4(r0,r1,r2,r3);
    float ps = r0*awc0 + r1*awc1 + r2*awc2 + r3*awc3;
    ps += __shfl_xor(ps, 1, 64);
    if (dq == 0) {
      const float sc = fminf(fmaxf(ps, -CLAMP_V), CLAMP_V);
      // segment-max subtraction dropped: s in [-5,5] -> exp safe; denominator
      // perturbation vs reference is ~2e-12 relative.
      sExp[(size_t)e*8 + h] = expf(sc);
    }
  }
}

// ============================================================================
// K3: CSR-by-dst build.
// ============================================================================
__global__ __launch_bounds__(256) void count_kernel(const int* __restrict__ eidx,
                                                    int* __restrict__ deg)
{
  const int e = blockIdx.x*256 + threadIdx.x;
  if (e < N_EDGES) atomicAdd(&deg[eidx[N_EDGES + e]], 1);
}

// 1024 threads, each owns 49 contiguous nodes: serial sum -> one 1024-wide
// scan (20 barriers total, vs ~980 in the old per-1024-chunk version) ->
// serial writeback of per-node prefixes.
__global__ __launch_bounds__(1024) void scan_kernel(const int* __restrict__ deg,
                                                    int* __restrict__ row_start,
                                                    int* __restrict__ cursor)
{
  __shared__ int buf[1024];
  const int t = threadIdx.x;
  const int beg = t * 49;
  const int end = (beg + 49 < N_NODES) ? beg + 49 : N_NODES;
  int sum = 0;
  for (int i = beg; i < end; i++) sum += deg[i];
  buf[t] = sum;
  __syncthreads();
  for (int off = 1; off < 1024; off <<= 1) {
    const int v = (t >= off) ? buf[t-off] : 0;
    __syncthreads();
    buf[t] += v;
    __syncthreads();
  }
  int run = (t == 0) ? 0 : buf[t-1];
  for (int i = beg; i < end; i++) {
    const int d = deg[i];
    row_start[i] = run; cursor[i] = run; run += d;
  }
  if (t == 1023) row_start[N_NODES] = buf[1023];
}

__global__ __launch_bounds__(256) void scatter_kernel(const int* __restrict__ eidx,
                                                      int* __restrict__ cursor,
                                                      int* __restrict__ edge_ord,
                                                      int* __restrict__ src_perm)
{
  const int e = blockIdx.x*256 + threadIdx.x;
  if (e < N_EDGES) {
    const int pos = atomicAdd(&cursor[eidx[N_EDGES + e]], 1);
    edge_ord[pos] = e;
    src_perm[pos] = eidx[e];          // kill the eidx[eid] dependent hop in K4
  }
}

// ============================================================================
// K4: node aggregation, SINGLE pass + 4x unroll for MLP.
// attn = e/D factors out: wV = (sum e*V + (sum e*e_t)@VeRow) / (D+1e-16).
// ============================================================================
__global__ __launch_bounds__(256) void node_kernel(
    const int*   __restrict__ row_start,
    const int*   __restrict__ edge_ord,
    const int*   __restrict__ src_perm,
    const float* __restrict__ sExp,
    const float* __restrict__ qkv,
    const float* __restrict__ wE,
    const float* __restrict__ VeRow,
    float* __restrict__ wV)
{
  __shared__ float sVe[512];                      // VeRow flat [d][h][c]
  const int t = threadIdx.x;
  for (int i = t; i < 512; i += 256) sVe[i] = VeRow[i];
  __syncthreads();
  const int lane = t & 63;
  const int node = blockIdx.x*4 + (t >> 6);
  const int h = lane >> 3;
  const int rs = row_start[node], re = row_start[node+1];
  float accU = 0.f, accR = 0.f, accD = 0.f;
  int j = rs;
  for (; j + 4 <= re; j += 4) {
    const int e0 = edge_ord[j],   e1 = edge_ord[j+1];
    const int e2 = edge_ord[j+2], e3 = edge_ord[j+3];
    const int s0 = src_perm[j],   s1 = src_perm[j+1];
    const int s2 = src_perm[j+2], s3 = src_perm[j+3];
    const float w0 = sExp[(size_t)e0*8 + h], w1 = sExp[(size_t)e1*8 + h];
    const float w2 = sExp[(size_t)e2*8 + h], w3 = sExp[(size_t)e3*8 + h];
    const float t0 = __builtin_nontemporal_load(&wE[(size_t)e0*64 + lane]);
    const float t1 = __builtin_nontemporal_load(&wE[(size_t)e1*64 + lane]);
    const float t2 = __builtin_nontemporal_load(&wE[(size_t)e2*64 + lane]);
    const float t3 = __builtin_nontemporal_load(&wE[(size_t)e3*64 + lane]);
    const float v0 = qkv[(size_t)s0*192 + 128 + lane];
    const float v1 = qkv[(size_t)s1*192 + 128 + lane];
    const float v2 = qkv[(size_t)s2*192 + 128 + lane];
    const float v3 = qkv[(size_t)s3*192 + 128 + lane];
    accD += (w0 + w1) + (w2 + w3);
    accU += w0*v0; accU += w1*v1; accU += w2*v2; accU += w3*v3;
    accR += w0*t0; accR += w1*t1; accR += w2*t2; accR += w3*t3;
  }
  for (; j < re; j++) {
    const int eid = edge_ord[j];
    const int src = src_perm[j];
    const float w = sExp[(size_t)eid*8 + h];
    accD += w;
    accU += w * qkv[(size_t)src*192 + 128 + lane];
    accR += w * __builtin_nontemporal_load(&wE[(size_t)eid*64 + lane]);
  }
  float val = accU;
  #pragma unroll
  for (int dd = 0; dd < 8; dd++) {
    const float rv = __shfl(accR, h*8 + dd, 64);
    val += rv * sVe[dd*64 + lane];
  }
  wV[(size_t)node*64 + lane] = val * (1.0f / (accD + 1e-16f));
}

// ============================================================================
// Workspace layout (bytes, needs ~71.0 MB):
//   qkv      @ 0           : 38,400,000
//   sExp     @ 38,400,000  : 25,600,000
//   deg      @ 64,000,000  :    200,000
//   row_start@ 64,200,000  :    200,004
//   cursor   @ 64,400,208  :    200,000
//   edge_ord @ 64,600,208  :  3,200,000
//   src_perm @ 67,800,208  :  3,200,000
// d_out: wV (50000*64) then wE (800000*64), fp32.
// ============================================================================
extern "C" void kernel_launch(void* const* d_in, const int* in_sizes, int n_in,
                              void* d_out, int out_size, void* d_ws, size_t ws_size,
                              hipStream_t stream)
{
  const float* x         = (const float*)d_in[0];
  const float* edge_attr = (const float*)d_in[1];
  const int*   eidx      = (const int*)  d_in[2];
  const float* Wq        = (const float*)d_in[3];
  const float* bq        = (const float*)d_in[4];
  const float* Wk        = (const float*)d_in[5];
  const float* bk        = (const float*)d_in[6];
  const float* We        = (const float*)d_in[7];
  const float* be        = (const float*)d_in[8];
  const float* Wv        = (const float*)d_in[9];
  const float* bv        = (const float*)d_in[10];
  const float* Aw        = (const float*)d_in[11];
  const float* VeRow     = (const float*)d_in[12];

  float* out = (float*)d_out;
  float* wV  = out;
  float* wE  = out + (size_t)N_NODES * 64;

  char* ws = (char*)d_ws;
  float* qkv      = (float*)(ws);
  float* sExp     = (float*)(ws + 38400000);
  int*   deg      = (int*)  (ws + 64000000);
  int*   row_start= (int*)  (ws + 64200000);
  int*   cursor   = (int*)  (ws + 64400208);
  int*   edge_ord = (int*)  (ws + 64600208);
  int*   src_perm = (int*)  (ws + 67800208);

  hipMemsetAsync(deg, 0, N_NODES * sizeof(int), stream);
  qkv_kernel    <<<3125,  192, 0, stream>>>(x, Wq, bq, Wk, bk, Wv, bv, qkv);
  edge_kernel   <<<6250,  256, 0, stream>>>(edge_attr, eidx, We, be, Aw, qkv, wE, sExp);
  count_kernel  <<<3125,  256, 0, stream>>>(eidx, deg);
  scan_kernel   <<<1,    1024, 0, stream>>>(deg, row_start, cursor);
  scatter_kernel<<<3125,  256, 0, stream>>>(eidx, cursor, edge_ord, src_perm);
  node_kernel   <<<12500, 256, 0, stream>>>(row_start, edge_ord, src_perm, sExp, qkv, wE, VeRow, wV);
}